// Round 3
// baseline (156.088 us; speedup 1.0000x reference)
//
#include <hip/hip_runtime.h>

#define NN 40000
#define NE 640000
#define CAP 64
#define BN_EPS 1e-5f

// ---------------- zero cursor + BN accumulators ----------------
__global__ __launch_bounds__(256) void k_zero(int* __restrict__ cursor, float* __restrict__ bn) {
    int i = blockIdx.x * 256 + threadIdx.x;
    if (i < NN) cursor[i] = 0;
    int j = i - NN;
    if (j >= 0 && j < 256) bn[j] = 0.f;
}

// ---------------- bucket edges by dst (1 int atomic per edge) ----------------
__global__ __launch_bounds__(256) void k_bucket(const int* __restrict__ ei, int* __restrict__ cursor,
                                                int* __restrict__ srclist) {
    int e = blockIdx.x * 256 + threadIdx.x;
    if (e >= NE) return;
    int s = ei[e];
    int d = ei[NE + e];
    int pos = atomicAdd(&cursor[d], 1);
    if (pos < CAP) srclist[d * CAP + pos] = s;
}

// ---------------- wave-per-node gather-sum: hbuf = (1+eps)*x + sum_neighbors x ----------------
// Latency fix (R3): issue a FIXED 32 independent row loads per wave into an explicitly
// live float2 v[32] register array (static indexing -> VGPRs, rule #20). Indices for
// i >= deg are clamped to node 0 (always valid, L1-hot after first touch) and their
// values masked out of the sum via fmaf(x, m, acc). No serial remainder chain; the
// rare deg>32 case (Poisson(16), P~1e-4) takes a wave-uniform serial tail.
__global__ __launch_bounds__(256) void k_gather(const float* __restrict__ x, const int* __restrict__ cursor,
                                                const int* __restrict__ srclist, const float* __restrict__ epsp,
                                                float* __restrict__ hbuf) {
    int wid = blockIdx.x * 4 + (threadIdx.x >> 6);   // one wave per dst node; grid*4 == NN exactly
    int lane = threadIdx.x & 63;
    const float2* xv = (const float2*)x;
    int deg = cursor[wid];
    deg = deg > CAP ? CAP : deg;
    int sv = srclist[wid * CAP + lane];              // full neighbor list in wave registers
    float2 self = xv[wid * 64 + lane];
    float e1 = 1.f + epsp[0];

    float2 v[32];
#pragma unroll
    for (int i = 0; i < 32; ++i) {
        int s = __builtin_amdgcn_readlane(sv, i);    // SALU broadcast
        s = (i < deg) ? s : 0;                       // s_cselect: safe clamped index
        v[i] = xv[(size_t)s * 64 + lane];            // 32 independent 512B row loads in flight
    }

    // 4 partial accumulator pairs for ILP; mask padded entries with fmaf(*, 0, *)
    float p0 = 0.f, p1 = 0.f, p2 = 0.f, p3 = 0.f;
    float q0 = 0.f, q1 = 0.f, q2 = 0.f, q3 = 0.f;
#pragma unroll
    for (int i = 0; i < 32; i += 4) {
        float m0 = (i + 0 < deg) ? 1.f : 0.f;
        float m1 = (i + 1 < deg) ? 1.f : 0.f;
        float m2 = (i + 2 < deg) ? 1.f : 0.f;
        float m3 = (i + 3 < deg) ? 1.f : 0.f;
        p0 = fmaf(v[i + 0].x, m0, p0);  q0 = fmaf(v[i + 0].y, m0, q0);
        p1 = fmaf(v[i + 1].x, m1, p1);  q1 = fmaf(v[i + 1].y, m1, q1);
        p2 = fmaf(v[i + 2].x, m2, p2);  q2 = fmaf(v[i + 2].y, m2, q2);
        p3 = fmaf(v[i + 3].x, m3, p3);  q3 = fmaf(v[i + 3].y, m3, q3);
    }
    float a0 = fmaf(self.x, e1, (p0 + p1) + (p2 + p3));
    float a1 = fmaf(self.y, e1, (q0 + q1) + (q2 + q3));

    if (deg > 32) {                                  // rare wave-uniform tail
        for (int i = 32; i < deg; ++i) {
            int s = __builtin_amdgcn_readlane(sv, i);
            float2 vv = xv[(size_t)s * 64 + lane];
            a0 += vv.x; a1 += vv.y;
        }
    }
    ((float2*)hbuf)[wid * 64 + lane] = make_float2(a0, a1);
}

// ---------------- fp32 vector GEMM: out[M,128] = A[M,128] @ W[128,128]^T + bias ----------------
// STATS: accumulate per-channel sum/sumsq of output (for BN).  BN: apply y=relu(a*scale+shift) to A on load.
template<bool STATS, bool BN>
__global__ __launch_bounds__(256) void k_gemm(const float* __restrict__ A, const float* __restrict__ W,
                                              const float* __restrict__ bias, float* __restrict__ out,
                                              const float* __restrict__ scale, const float* __restrict__ shift,
                                              float* __restrict__ bnsum, float* __restrict__ bnsumsq) {
    __shared__ float sA[64 * 65];    // 64 rows x 64 k (stride 65: <=2-way bank aliasing, free)
    __shared__ float sW[128 * 65];   // 128 cols x 64 k
    const int tid = threadIdx.x;
    const int tx = tid & 15;
    const int ty = tid >> 4;
    const int rb = blockIdx.x * 64;  // 40000 % 64 == 0: no row guards needed

    float acc[4][8];
#pragma unroll
    for (int i = 0; i < 4; ++i)
#pragma unroll
        for (int j = 0; j < 8; ++j) acc[i][j] = 0.f;

    for (int kb = 0; kb < 128; kb += 64) {
        __syncthreads();
        // stage A-tile (64x64), optionally with BN+ReLU fused
#pragma unroll
        for (int it = 0; it < 4; ++it) {
            int idx = it * 256 + tid;
            int r = idx >> 4;
            int kq = idx & 15;
            float4 v = *(const float4*)&A[(size_t)(rb + r) * 128 + kb + kq * 4];
            if (BN) {
                float4 sc = *(const float4*)&scale[kb + kq * 4];
                float4 sh = *(const float4*)&shift[kb + kq * 4];
                v.x = fmaxf(0.f, fmaf(v.x, sc.x, sh.x));
                v.y = fmaxf(0.f, fmaf(v.y, sc.y, sh.y));
                v.z = fmaxf(0.f, fmaf(v.z, sc.z, sh.z));
                v.w = fmaxf(0.f, fmaf(v.w, sc.w, sh.w));
            }
            float* d = &sA[r * 65 + kq * 4];
            d[0] = v.x; d[1] = v.y; d[2] = v.z; d[3] = v.w;
        }
        // stage W-tile (128x64), row-major as given (out[c] = sum_k A[k]*W[c][k])
#pragma unroll
        for (int it = 0; it < 8; ++it) {
            int idx = it * 256 + tid;
            int c = idx >> 4;
            int kq = idx & 15;
            float4 v = *(const float4*)&W[c * 128 + kb + kq * 4];
            float* d = &sW[c * 65 + kq * 4];
            d[0] = v.x; d[1] = v.y; d[2] = v.z; d[3] = v.w;
        }
        __syncthreads();
#pragma unroll 4
        for (int k = 0; k < 64; ++k) {
            float a[4], w[8];
#pragma unroll
            for (int i = 0; i < 4; ++i) a[i] = sA[(ty * 4 + i) * 65 + k];
#pragma unroll
            for (int j = 0; j < 4; ++j) {
                w[j]     = sW[(tx * 4 + j) * 65 + k];
                w[j + 4] = sW[(tx * 4 + 64 + j) * 65 + k];
            }
#pragma unroll
            for (int i = 0; i < 4; ++i)
#pragma unroll
                for (int j = 0; j < 8; ++j)
                    acc[i][j] = fmaf(a[i], w[j], acc[i][j]);
        }
    }

    const int c0 = tx * 4, c1 = tx * 4 + 64;
    float4 b0 = *(const float4*)&bias[c0];
    float4 b1v = *(const float4*)&bias[c1];
    float cs[8], cq[8];
#pragma unroll
    for (int j = 0; j < 8; ++j) { cs[j] = 0.f; cq[j] = 0.f; }
#pragma unroll
    for (int i = 0; i < 4; ++i) {
        int row = rb + ty * 4 + i;
        float4 v0, v1;
        v0.x = acc[i][0] + b0.x;  v0.y = acc[i][1] + b0.y;  v0.z = acc[i][2] + b0.z;  v0.w = acc[i][3] + b0.w;
        v1.x = acc[i][4] + b1v.x; v1.y = acc[i][5] + b1v.y; v1.z = acc[i][6] + b1v.z; v1.w = acc[i][7] + b1v.w;
        *(float4*)&out[(size_t)row * 128 + c0] = v0;
        *(float4*)&out[(size_t)row * 128 + c1] = v1;
        if (STATS) {
            cs[0] += v0.x; cq[0] += v0.x * v0.x;
            cs[1] += v0.y; cq[1] += v0.y * v0.y;
            cs[2] += v0.z; cq[2] += v0.z * v0.z;
            cs[3] += v0.w; cq[3] += v0.w * v0.w;
            cs[4] += v1.x; cq[4] += v1.x * v1.x;
            cs[5] += v1.y; cq[5] += v1.y * v1.y;
            cs[6] += v1.z; cq[6] += v1.z * v1.z;
            cs[7] += v1.w; cq[7] += v1.w * v1.w;
        }
    }
    if (STATS) {
        __syncthreads();           // everyone done reading sA/sW
        float* rs = sA;            // reuse LDS: 256 threads x 8 floats
        float* rq = sW;
#pragma unroll
        for (int j = 0; j < 8; ++j) { rs[tid * 8 + j] = cs[j]; rq[tid * 8 + j] = cq[j]; }
        __syncthreads();
        if (tid < 128) {
            int txx = tid >> 3, j = tid & 7;
            int c = (j < 4) ? (txx * 4 + j) : (txx * 4 + 60 + j);
            float s = 0.f, q = 0.f;
#pragma unroll
            for (int t = 0; t < 16; ++t) {
                s += rs[(t * 16 + txx) * 8 + j];
                q += rq[(t * 16 + txx) * 8 + j];
            }
            atomicAdd(&bnsum[c], s);
            atomicAdd(&bnsumsq[c], q);
        }
    }
}

// ---------------- finalize BN: scale/shift per channel ----------------
__global__ void k_bnfin(const float* __restrict__ bnsum, const float* __restrict__ bnsumsq,
                        const float* __restrict__ gamma, const float* __restrict__ beta,
                        float* __restrict__ scale, float* __restrict__ shift) {
    int c = threadIdx.x;
    if (c < 128) {
        float mu = bnsum[c] * (1.0f / NN);
        float var = bnsumsq[c] * (1.0f / NN) - mu * mu;
        float rs = rsqrtf(var + BN_EPS);
        float g = rs * gamma[c];
        scale[c] = g;
        shift[c] = beta[c] - mu * g;
    }
}

extern "C" void kernel_launch(void* const* d_in, const int* in_sizes, int n_in,
                              void* d_out, int out_size, void* d_ws, size_t ws_size,
                              hipStream_t stream) {
    const float* x     = (const float*)d_in[0];
    const int*   ei    = (const int*)d_in[1];
    const float* W1    = (const float*)d_in[2];
    const float* b1    = (const float*)d_in[3];
    const float* gamma = (const float*)d_in[4];
    const float* beta  = (const float*)d_in[5];
    const float* W2    = (const float*)d_in[6];
    const float* b2    = (const float*)d_in[7];
    const float* eps   = (const float*)d_in[8];

    char* ws = (char*)d_ws;
    // ws layout (all offsets 256B-aligned): cursor[40000] | srclist[40000*64] | hbuf[40000*128] | bn[512]
    int*   cursor  = (int*)(ws + 0);
    int*   srclist = (int*)(ws + 160000);
    float* hbuf    = (float*)(ws + 10400000);
    float* bn      = (float*)(ws + 30880000);
    float* bnsum   = bn;
    float* bnsumsq = bn + 128;
    float* scale   = bn + 256;
    float* shift   = bn + 384;
    float* h1      = (float*)d_out;   // reuse d_out as h1 scratch (in-place-safe GEMM2)

    k_zero<<<158, 256, 0, stream>>>(cursor, bn);
    k_bucket<<<2500, 256, 0, stream>>>(ei, cursor, srclist);
    k_gather<<<10000, 256, 0, stream>>>(x, cursor, srclist, eps, hbuf);
    k_gemm<true, false><<<625, 256, 0, stream>>>(hbuf, W1, b1, h1, nullptr, nullptr, bnsum, bnsumsq);
    k_bnfin<<<1, 128, 0, stream>>>(bnsum, bnsumsq, gamma, beta, scale, shift);
    k_gemm<false, true><<<625, 256, 0, stream>>>(h1, W2, b2, (float*)d_out, scale, shift, nullptr, nullptr);
}

// Round 4
// 123.453 us; speedup vs baseline: 1.2644x; 1.2644x over previous
//
#include <hip/hip_runtime.h>

#define NN 40000
#define NE 640000
#define BN_EPS 1e-5f

typedef __attribute__((ext_vector_type(8))) short bf16x8;
typedef __attribute__((ext_vector_type(4))) float f32x4;
typedef unsigned int uint;
typedef unsigned short ushort;

__device__ __forceinline__ float blo(uint u) { return __uint_as_float(u << 16); }
__device__ __forceinline__ float bhi(uint u) { return __uint_as_float(u & 0xFFFF0000u); }
__device__ __forceinline__ uint bpack(float lo, float hi) {
    uint a = __float_as_uint(lo); a = (a + 0x7FFFu + ((a >> 16) & 1u)) >> 16;        // RNE
    uint b = __float_as_uint(hi); b = (b + 0x7FFFu + ((b >> 16) & 1u)) & 0xFFFF0000u;
    return a | b;
}
__device__ __forceinline__ uint4 cvt8(const float4* f4, int i) {
    float4 p = f4[i * 2], q = f4[i * 2 + 1];
    uint4 o;
    o.x = bpack(p.x, p.y); o.y = bpack(p.z, p.w);
    o.z = bpack(q.x, q.y); o.w = bpack(q.z, q.w);
    return o;
}

// ---------------- fused prologue: zero cnt+bn, x->bf16, W1->bf16 ----------------
__global__ __launch_bounds__(256) void k_pre(const float* __restrict__ x, const float* __restrict__ W1,
                                             int* __restrict__ cnt, float* __restrict__ bn,
                                             uint* __restrict__ xb, uint* __restrict__ w1b) {
    int b = blockIdx.x, t = threadIdx.x;
    if (b < 157) {
        int i = b * 256 + t;
        if (i < NN) cnt[i] = 0;
        if (b == 156) bn[t] = 0.f;                     // bnsum[128]+bnsumsq[128]
    } else if (b < 2657) {
        int i = (b - 157) * 256 + t;                   // 640000 groups of 8 ch
        ((uint4*)xb)[i] = cvt8((const float4*)x, i);
    } else {
        int i = (b - 2657) * 256 + t;                  // 2048 groups of 8 (128x128)
        ((uint4*)w1b)[i] = cvt8((const float4*)W1, i);
    }
}

// ---------------- bucket edges by dst (1 int atomic per edge), u16 src ids ----------------
__global__ __launch_bounds__(256) void k_bucket(const int* __restrict__ ei, int* __restrict__ cnt,
                                                ushort* __restrict__ srcl) {
    int e = blockIdx.x * 256 + threadIdx.x;
    if (e >= NE) return;
    int s = ei[e];
    int d = ei[NE + e];
    int pos = atomicAdd(&cnt[d], 1);
    if (pos < 64) srcl[d * 64 + pos] = (ushort)s;
}

// ---------------- wave-per-node bf16 gather: hb = bf16((1+eps)*x + sum_N x) ----------------
__global__ __launch_bounds__(256) void k_gather(const uint* __restrict__ xbv, const int* __restrict__ cnt,
                                                const ushort* __restrict__ srcl, const float* __restrict__ epsp,
                                                uint* __restrict__ hb) {
    int wid = blockIdx.x * 4 + (threadIdx.x >> 6);    // one wave per node
    int lane = threadIdx.x & 63;
    int deg = cnt[wid]; deg = deg > 64 ? 64 : deg;
    int sv = srcl[wid * 64 + lane];                   // neighbor ids in wave registers
    uint su = xbv[wid * 64 + lane];                   // self row (2 ch per lane)
    float e1 = 1.f + epsp[0];
    float a0 = blo(su) * e1, a1 = bhi(su) * e1;
    float c0 = 0.f, c1 = 0.f;
    int full = deg & ~7;
    for (int i = 0; i < full; i += 8) {
        int s0 = __builtin_amdgcn_readlane(sv, i);
        int s1 = __builtin_amdgcn_readlane(sv, i + 1);
        int s2 = __builtin_amdgcn_readlane(sv, i + 2);
        int s3 = __builtin_amdgcn_readlane(sv, i + 3);
        int s4 = __builtin_amdgcn_readlane(sv, i + 4);
        int s5 = __builtin_amdgcn_readlane(sv, i + 5);
        int s6 = __builtin_amdgcn_readlane(sv, i + 6);
        int s7 = __builtin_amdgcn_readlane(sv, i + 7);
        uint v0 = xbv[(size_t)s0 * 64 + lane];
        uint v1 = xbv[(size_t)s1 * 64 + lane];
        uint v2 = xbv[(size_t)s2 * 64 + lane];
        uint v3 = xbv[(size_t)s3 * 64 + lane];
        uint v4 = xbv[(size_t)s4 * 64 + lane];
        uint v5 = xbv[(size_t)s5 * 64 + lane];
        uint v6 = xbv[(size_t)s6 * 64 + lane];
        uint v7 = xbv[(size_t)s7 * 64 + lane];
        a0 += blo(v0) + blo(v1) + blo(v2) + blo(v3);
        c0 += blo(v4) + blo(v5) + blo(v6) + blo(v7);
        a1 += bhi(v0) + bhi(v1) + bhi(v2) + bhi(v3);
        c1 += bhi(v4) + bhi(v5) + bhi(v6) + bhi(v7);
    }
    if (deg & 7) {                                    // one masked tail batch (wave-uniform branch)
#pragma unroll
        for (int j = 0; j < 8; ++j) {
            int idx = full + j;
            int s = __builtin_amdgcn_readlane(sv, idx);
            bool ok = idx < deg;
            s = ok ? s : 0;
            uint v = xbv[(size_t)s * 64 + lane];
            a0 += ok ? blo(v) : 0.f;
            a1 += ok ? bhi(v) : 0.f;
        }
    }
    hb[wid * 64 + lane] = bpack(a0 + c0, a1 + c1);
}

// ---------------- GEMM1 (MFMA bf16): h1 = hb @ W1b^T + b1, fused BN stats ----------------
// mfma_f32_16x16x32_bf16 fragments: A[row=l&15][k=(l>>4)*8+j], B[k=(l>>4)*8+j][col=l&15],
// C/D: col=l&15, row=(l>>4)*4+i  [verified layout, learn_hip m89/m91]
__global__ __launch_bounds__(256) void k_mm1(const ushort* __restrict__ hb, const ushort* __restrict__ w1b,
                                             const float* __restrict__ b1, float* __restrict__ h1,
                                             float* __restrict__ bnsum, float* __restrict__ bnsumsq) {
    __shared__ float rs[256 * 8];
    __shared__ float rq[256 * 8];
    const int tid = threadIdx.x;
    const int wave = tid >> 6;
    const int lane = tid & 63;
    const int lr = lane & 15;
    const int lk = lane >> 4;
    const int r0 = (blockIdx.x * 4 + wave) * 16;     // 625 blocks * 4 waves * 16 rows = 40000

    bf16x8 a[4];
#pragma unroll
    for (int ks = 0; ks < 4; ++ks)
        a[ks] = *reinterpret_cast<const bf16x8*>(&hb[(size_t)(r0 + lr) * 128 + ks * 32 + lk * 8]);

    f32x4 acc[8];
#pragma unroll
    for (int t = 0; t < 8; ++t) { acc[t][0] = 0.f; acc[t][1] = 0.f; acc[t][2] = 0.f; acc[t][3] = 0.f; }

#pragma unroll
    for (int t = 0; t < 8; ++t) {
        const ushort* wrow = &w1b[(size_t)(t * 16 + lr) * 128];
#pragma unroll
        for (int ks = 0; ks < 4; ++ks) {
            bf16x8 bfr = *reinterpret_cast<const bf16x8*>(&wrow[ks * 32 + lk * 8]);
            acc[t] = __builtin_amdgcn_mfma_f32_16x16x32_bf16(a[ks], bfr, acc[t], 0, 0, 0);
        }
    }
#pragma unroll
    for (int t = 0; t < 8; ++t) {
        float bias = b1[t * 16 + lr];
        float s = 0.f, q = 0.f;
#pragma unroll
        for (int i = 0; i < 4; ++i) {
            float v = acc[t][i] + bias;
            h1[(size_t)(r0 + lk * 4 + i) * 128 + t * 16 + lr] = v;
            s += v; q += v * v;
        }
        rs[tid * 8 + t] = s;
        rq[tid * 8 + t] = q;
    }
    __syncthreads();
    if (tid < 128) {
        int c = tid, t = c >> 4, cr = c & 15;
        float s = 0.f, q = 0.f;
#pragma unroll
        for (int w = 0; w < 4; ++w)
#pragma unroll
            for (int g = 0; g < 4; ++g) {
                int src = w * 64 + g * 16 + cr;
                s += rs[src * 8 + t];
                q += rq[src * 8 + t];
            }
        atomicAdd(&bnsum[c], s);
        atomicAdd(&bnsumsq[c], q);
    }
}

// ---------------- finalize BN: scale/shift per channel ----------------
__global__ void k_bnfin(const float* __restrict__ bnsum, const float* __restrict__ bnsumsq,
                        const float* __restrict__ gamma, const float* __restrict__ beta,
                        float* __restrict__ scale, float* __restrict__ shift) {
    int c = threadIdx.x;
    if (c < 128) {
        float mu = bnsum[c] * (1.0f / NN);
        float var = bnsumsq[c] * (1.0f / NN) - mu * mu;
        float rs = rsqrtf(var + BN_EPS);
        float g = rs * gamma[c];
        scale[c] = g;
        shift[c] = beta[c] - mu * g;
    }
}

// ---------------- GEMM2 (f32 vector, known-correct): out = relu(bn(h1)) @ W2^T + b2 ----------------
__global__ __launch_bounds__(256) void k_gemm2(const float* __restrict__ A, const float* __restrict__ W,
                                               const float* __restrict__ bias, float* __restrict__ out,
                                               const float* __restrict__ scale, const float* __restrict__ shift) {
    __shared__ float sA[64 * 65];
    __shared__ float sW[128 * 65];
    const int tid = threadIdx.x;
    const int tx = tid & 15;
    const int ty = tid >> 4;
    const int rb = blockIdx.x * 64;

    float acc[4][8];
#pragma unroll
    for (int i = 0; i < 4; ++i)
#pragma unroll
        for (int j = 0; j < 8; ++j) acc[i][j] = 0.f;

    for (int kb = 0; kb < 128; kb += 64) {
        __syncthreads();
#pragma unroll
        for (int it = 0; it < 4; ++it) {
            int idx = it * 256 + tid;
            int r = idx >> 4;
            int kq = idx & 15;
            float4 v = *(const float4*)&A[(size_t)(rb + r) * 128 + kb + kq * 4];
            float4 sc = *(const float4*)&scale[kb + kq * 4];
            float4 sh = *(const float4*)&shift[kb + kq * 4];
            v.x = fmaxf(0.f, fmaf(v.x, sc.x, sh.x));
            v.y = fmaxf(0.f, fmaf(v.y, sc.y, sh.y));
            v.z = fmaxf(0.f, fmaf(v.z, sc.z, sh.z));
            v.w = fmaxf(0.f, fmaf(v.w, sc.w, sh.w));
            float* d = &sA[r * 65 + kq * 4];
            d[0] = v.x; d[1] = v.y; d[2] = v.z; d[3] = v.w;
        }
#pragma unroll
        for (int it = 0; it < 8; ++it) {
            int idx = it * 256 + tid;
            int c = idx >> 4;
            int kq = idx & 15;
            float4 v = *(const float4*)&W[c * 128 + kb + kq * 4];
            float* d = &sW[c * 65 + kq * 4];
            d[0] = v.x; d[1] = v.y; d[2] = v.z; d[3] = v.w;
        }
        __syncthreads();
#pragma unroll 4
        for (int k = 0; k < 64; ++k) {
            float a[4], w[8];
#pragma unroll
            for (int i = 0; i < 4; ++i) a[i] = sA[(ty * 4 + i) * 65 + k];
#pragma unroll
            for (int j = 0; j < 4; ++j) {
                w[j]     = sW[(tx * 4 + j) * 65 + k];
                w[j + 4] = sW[(tx * 4 + 64 + j) * 65 + k];
            }
#pragma unroll
            for (int i = 0; i < 4; ++i)
#pragma unroll
                for (int j = 0; j < 8; ++j)
                    acc[i][j] = fmaf(a[i], w[j], acc[i][j]);
        }
    }

    const int c0 = tx * 4, c1 = tx * 4 + 64;
    float4 b0 = *(const float4*)&bias[c0];
    float4 b1v = *(const float4*)&bias[c1];
#pragma unroll
    for (int i = 0; i < 4; ++i) {
        int row = rb + ty * 4 + i;
        float4 v0, v1;
        v0.x = acc[i][0] + b0.x;  v0.y = acc[i][1] + b0.y;  v0.z = acc[i][2] + b0.z;  v0.w = acc[i][3] + b0.w;
        v1.x = acc[i][4] + b1v.x; v1.y = acc[i][5] + b1v.y; v1.z = acc[i][6] + b1v.z; v1.w = acc[i][7] + b1v.w;
        *(float4*)&out[(size_t)row * 128 + c0] = v0;
        *(float4*)&out[(size_t)row * 128 + c1] = v1;
    }
}

extern "C" void kernel_launch(void* const* d_in, const int* in_sizes, int n_in,
                              void* d_out, int out_size, void* d_ws, size_t ws_size,
                              hipStream_t stream) {
    const float* x     = (const float*)d_in[0];
    const int*   ei    = (const int*)d_in[1];
    const float* W1    = (const float*)d_in[2];
    const float* b1    = (const float*)d_in[3];
    const float* gamma = (const float*)d_in[4];
    const float* beta  = (const float*)d_in[5];
    const float* W2    = (const float*)d_in[6];
    const float* b2    = (const float*)d_in[7];
    const float* eps   = (const float*)d_in[8];

    char* ws = (char*)d_ws;
    // ws layout (256B-aligned): cnt[40000] | srcl u16[40000*64] | xb bf16[40000*128] |
    //                           hb bf16[40000*128] | w1b bf16[128*128] | bn[512]
    int*    cnt  = (int*)(ws + 0);
    ushort* srcl = (ushort*)(ws + 196608);
    uint*   xb   = (uint*)(ws + 5373952);
    uint*   hb   = (uint*)(ws + 15728640);
    uint*   w1b  = (uint*)(ws + 26083328);
    float*  bn   = (float*)(ws + 26148864);
    float* bnsum   = bn;
    float* bnsumsq = bn + 128;
    float* scale   = bn + 256;
    float* shift   = bn + 384;
    float* h1      = (float*)d_out;   // h1 scratch in d_out (GEMM2 is in-place-safe per 64-row tile)

    k_pre<<<2665, 256, 0, stream>>>(x, W1, cnt, bn, xb, w1b);
    k_bucket<<<2500, 256, 0, stream>>>(ei, cnt, srcl);
    k_gather<<<10000, 256, 0, stream>>>(xb, cnt, srcl, eps, hb);
    k_mm1<<<625, 256, 0, stream>>>((const ushort*)hb, (const ushort*)w1b, b1, h1, bnsum, bnsumsq);
    k_bnfin<<<1, 128, 0, stream>>>(bnsum, bnsumsq, gamma, beta, scale, shift);
    k_gemm2<<<625, 256, 0, stream>>>(h1, W2, b2, (float*)d_out, scale, shift);
}

// Round 5
// 107.661 us; speedup vs baseline: 1.4498x; 1.1467x over previous
//
#include <hip/hip_runtime.h>

#define NN 40000
#define NE 640000
#define BN_EPS 1e-5f

typedef __attribute__((ext_vector_type(8))) short bf16x8;
typedef __attribute__((ext_vector_type(4))) float f32x4;
typedef unsigned int uint;
typedef unsigned short ushort;

__device__ __forceinline__ float blo(uint u) { return __uint_as_float(u << 16); }
__device__ __forceinline__ float bhi(uint u) { return __uint_as_float(u & 0xFFFF0000u); }
__device__ __forceinline__ uint bpack(float lo, float hi) {
    uint a = __float_as_uint(lo); a = (a + 0x7FFFu + ((a >> 16) & 1u)) >> 16;        // RNE
    uint b = __float_as_uint(hi); b = (b + 0x7FFFu + ((b >> 16) & 1u)) & 0xFFFF0000u;
    return a | b;
}
__device__ __forceinline__ ushort b1pack(float v) {
    uint u = __float_as_uint(v); return (ushort)((u + 0x7FFFu + ((u >> 16) & 1u)) >> 16);
}
__device__ __forceinline__ uint4 cvt8(const float4* f4, int i) {
    float4 p = f4[i * 2], q = f4[i * 2 + 1];
    uint4 o;
    o.x = bpack(p.x, p.y); o.y = bpack(p.z, p.w);
    o.z = bpack(q.x, q.y); o.w = bpack(q.z, q.w);
    return o;
}

// ---------------- fused prologue: zero cnt+bn, x->bf16, W1->bf16, W2->bf16 ----------------
__global__ __launch_bounds__(256) void k_pre(const float* __restrict__ x, const float* __restrict__ W1,
                                             const float* __restrict__ W2,
                                             int* __restrict__ cnt, float* __restrict__ bn,
                                             uint* __restrict__ xb, uint* __restrict__ w1b,
                                             uint* __restrict__ w2b) {
    int b = blockIdx.x, t = threadIdx.x;
    if (b < 157) {
        int i = b * 256 + t;
        if (i < NN) cnt[i] = 0;
        if (b == 156) bn[t] = 0.f;                     // bnsum[128]+bnsumsq[128]
    } else if (b < 2657) {
        int i = (b - 157) * 256 + t;                   // 640000 groups of 8 ch
        ((uint4*)xb)[i] = cvt8((const float4*)x, i);
    } else if (b < 2665) {
        int i = (b - 2657) * 256 + t;                  // 2048 groups (128x128)
        ((uint4*)w1b)[i] = cvt8((const float4*)W1, i);
    } else {
        int i = (b - 2665) * 256 + t;
        ((uint4*)w2b)[i] = cvt8((const float4*)W2, i);
    }
}

// ---------------- bucket edges by dst (1 int atomic per edge), u16 src ids ----------------
__global__ __launch_bounds__(256) void k_bucket(const int* __restrict__ ei, int* __restrict__ cnt,
                                                ushort* __restrict__ srcl) {
    int e = blockIdx.x * 256 + threadIdx.x;
    if (e >= NE) return;
    int s = ei[e];
    int d = ei[NE + e];
    int pos = atomicAdd(&cnt[d], 1);
    if (pos < 64) srcl[d * 64 + pos] = (ushort)s;
}

// ---------------- wave-per-node bf16 gather: hb = bf16((1+eps)*x + sum_N x) ----------------
__global__ __launch_bounds__(256) void k_gather(const uint* __restrict__ xbv, const int* __restrict__ cnt,
                                                const ushort* __restrict__ srcl, const float* __restrict__ epsp,
                                                uint* __restrict__ hb) {
    int wid = blockIdx.x * 4 + (threadIdx.x >> 6);    // one wave per node
    int lane = threadIdx.x & 63;
    int deg = cnt[wid]; deg = deg > 64 ? 64 : deg;
    int sv = srcl[wid * 64 + lane];                   // neighbor ids in wave registers
    uint su = xbv[wid * 64 + lane];                   // self row (2 ch per lane)
    float e1 = 1.f + epsp[0];
    float a0 = blo(su) * e1, a1 = bhi(su) * e1;
    float c0 = 0.f, c1 = 0.f;
    int full = deg & ~7;
    for (int i = 0; i < full; i += 8) {
        int s0 = __builtin_amdgcn_readlane(sv, i);
        int s1 = __builtin_amdgcn_readlane(sv, i + 1);
        int s2 = __builtin_amdgcn_readlane(sv, i + 2);
        int s3 = __builtin_amdgcn_readlane(sv, i + 3);
        int s4 = __builtin_amdgcn_readlane(sv, i + 4);
        int s5 = __builtin_amdgcn_readlane(sv, i + 5);
        int s6 = __builtin_amdgcn_readlane(sv, i + 6);
        int s7 = __builtin_amdgcn_readlane(sv, i + 7);
        uint v0 = xbv[(size_t)s0 * 64 + lane];
        uint v1 = xbv[(size_t)s1 * 64 + lane];
        uint v2 = xbv[(size_t)s2 * 64 + lane];
        uint v3 = xbv[(size_t)s3 * 64 + lane];
        uint v4 = xbv[(size_t)s4 * 64 + lane];
        uint v5 = xbv[(size_t)s5 * 64 + lane];
        uint v6 = xbv[(size_t)s6 * 64 + lane];
        uint v7 = xbv[(size_t)s7 * 64 + lane];
        a0 += blo(v0) + blo(v1) + blo(v2) + blo(v3);
        c0 += blo(v4) + blo(v5) + blo(v6) + blo(v7);
        a1 += bhi(v0) + bhi(v1) + bhi(v2) + bhi(v3);
        c1 += bhi(v4) + bhi(v5) + bhi(v6) + bhi(v7);
    }
    if (deg & 7) {                                    // one masked tail batch (wave-uniform branch)
#pragma unroll
        for (int j = 0; j < 8; ++j) {
            int idx = full + j;
            int s = __builtin_amdgcn_readlane(sv, idx);
            bool ok = idx < deg;
            s = ok ? s : 0;
            uint v = xbv[(size_t)s * 64 + lane];
            a0 += ok ? blo(v) : 0.f;
            a1 += ok ? bhi(v) : 0.f;
        }
    }
    hb[wid * 64 + lane] = bpack(a0 + c0, a1 + c1);
}

// ---------------- GEMM1 (MFMA bf16): h1b = bf16(hb @ W1b^T + b1), fused BN stats ----------------
// mfma_f32_16x16x32_bf16 fragments: A[row=l&15][k=(l>>4)*8+j], B[k=(l>>4)*8+j][col=l&15],
// C/D: col=l&15, row=(l>>4)*4+i  [verified layout, learn_hip m89/m91]
__global__ __launch_bounds__(256) void k_mm1(const ushort* __restrict__ hb, const ushort* __restrict__ w1b,
                                             const float* __restrict__ b1, ushort* __restrict__ h1b,
                                             float* __restrict__ bnsum, float* __restrict__ bnsumsq) {
    __shared__ float rs[256 * 8];
    __shared__ float rq[256 * 8];
    const int tid = threadIdx.x;
    const int wave = tid >> 6;
    const int lane = tid & 63;
    const int lr = lane & 15;
    const int lk = lane >> 4;
    const int r0 = (blockIdx.x * 4 + wave) * 16;     // 625 blocks * 4 waves * 16 rows = 40000

    bf16x8 a[4];
#pragma unroll
    for (int ks = 0; ks < 4; ++ks)
        a[ks] = *reinterpret_cast<const bf16x8*>(&hb[(size_t)(r0 + lr) * 128 + ks * 32 + lk * 8]);

    f32x4 acc[8];
#pragma unroll
    for (int t = 0; t < 8; ++t) { acc[t][0] = 0.f; acc[t][1] = 0.f; acc[t][2] = 0.f; acc[t][3] = 0.f; }

#pragma unroll
    for (int t = 0; t < 8; ++t) {
        const ushort* wrow = &w1b[(size_t)(t * 16 + lr) * 128];
#pragma unroll
        for (int ks = 0; ks < 4; ++ks) {
            bf16x8 bfr = *reinterpret_cast<const bf16x8*>(&wrow[ks * 32 + lk * 8]);
            acc[t] = __builtin_amdgcn_mfma_f32_16x16x32_bf16(a[ks], bfr, acc[t], 0, 0, 0);
        }
    }
#pragma unroll
    for (int t = 0; t < 8; ++t) {
        float bias = b1[t * 16 + lr];
        float s = 0.f, q = 0.f;
#pragma unroll
        for (int i = 0; i < 4; ++i) {
            float v = acc[t][i] + bias;
            h1b[(size_t)(r0 + lk * 4 + i) * 128 + t * 16 + lr] = b1pack(v);
            s += v; q += v * v;
        }
        rs[tid * 8 + t] = s;
        rq[tid * 8 + t] = q;
    }
    __syncthreads();
    if (tid < 128) {
        int c = tid, t = c >> 4, cr = c & 15;
        float s = 0.f, q = 0.f;
#pragma unroll
        for (int w = 0; w < 4; ++w)
#pragma unroll
            for (int g = 0; g < 4; ++g) {
                int src = w * 64 + g * 16 + cr;
                s += rs[src * 8 + t];
                q += rq[src * 8 + t];
            }
        atomicAdd(&bnsum[c], s);
        atomicAdd(&bnsumsq[c], q);
    }
}

// ---------------- GEMM2 (MFMA bf16): out = relu(bn(h1)) @ W2b^T + b2, BN finalized inline ----------------
__global__ __launch_bounds__(256) void k_mm2(const ushort* __restrict__ h1b, const ushort* __restrict__ w2b,
                                             const float* __restrict__ b2,
                                             const float* __restrict__ bnsum, const float* __restrict__ bnsumsq,
                                             const float* __restrict__ gamma, const float* __restrict__ beta,
                                             float* __restrict__ out) {
    __shared__ float ssc[128], ssh[128];
    const int tid = threadIdx.x;
    if (tid < 128) {
        float mu = bnsum[tid] * (1.0f / NN);
        float var = bnsumsq[tid] * (1.0f / NN) - mu * mu;
        float rsv = rsqrtf(var + BN_EPS);
        float g = rsv * gamma[tid];
        ssc[tid] = g;
        ssh[tid] = beta[tid] - mu * g;
    }
    __syncthreads();

    const int wave = tid >> 6;
    const int lane = tid & 63;
    const int lr = lane & 15;
    const int lk = lane >> 4;
    const int r0 = (blockIdx.x * 4 + wave) * 16;

    bf16x8 a[4];
#pragma unroll
    for (int ks = 0; ks < 4; ++ks) {
        int kbase = ks * 32 + lk * 8;
        bf16x8 raw = *reinterpret_cast<const bf16x8*>(&h1b[(size_t)(r0 + lr) * 128 + kbase]);
        bf16x8 o;
#pragma unroll
        for (int j = 0; j < 8; ++j) {
            float v = __uint_as_float(((uint)(ushort)raw[j]) << 16);
            v = fmaxf(0.f, fmaf(v, ssc[kbase + j], ssh[kbase + j]));   // LDS broadcast per 16-lane group
            o[j] = (short)b1pack(v);
        }
        a[ks] = o;
    }

    f32x4 acc[8];
#pragma unroll
    for (int t = 0; t < 8; ++t) { acc[t][0] = 0.f; acc[t][1] = 0.f; acc[t][2] = 0.f; acc[t][3] = 0.f; }

#pragma unroll
    for (int t = 0; t < 8; ++t) {
        const ushort* wrow = &w2b[(size_t)(t * 16 + lr) * 128];
#pragma unroll
        for (int ks = 0; ks < 4; ++ks) {
            bf16x8 bfr = *reinterpret_cast<const bf16x8*>(&wrow[ks * 32 + lk * 8]);
            acc[t] = __builtin_amdgcn_mfma_f32_16x16x32_bf16(a[ks], bfr, acc[t], 0, 0, 0);
        }
    }
#pragma unroll
    for (int t = 0; t < 8; ++t) {
        float bias = b2[t * 16 + lr];
#pragma unroll
        for (int i = 0; i < 4; ++i)
            out[(size_t)(r0 + lk * 4 + i) * 128 + t * 16 + lr] = acc[t][i] + bias;
    }
}

extern "C" void kernel_launch(void* const* d_in, const int* in_sizes, int n_in,
                              void* d_out, int out_size, void* d_ws, size_t ws_size,
                              hipStream_t stream) {
    const float* x     = (const float*)d_in[0];
    const int*   ei    = (const int*)d_in[1];
    const float* W1    = (const float*)d_in[2];
    const float* b1    = (const float*)d_in[3];
    const float* gamma = (const float*)d_in[4];
    const float* beta  = (const float*)d_in[5];
    const float* W2    = (const float*)d_in[6];
    const float* b2    = (const float*)d_in[7];
    const float* eps   = (const float*)d_in[8];

    char* ws = (char*)d_ws;
    // ws layout (256B-aligned): cnt[40000]i32 | srcl u16[40000*64] | xb bf16[40000*128] |
    //   hb bf16[40000*128] | h1b bf16[40000*128] | w1b bf16[128*128] | w2b bf16[128*128] | bn f32[256]
    int*    cnt  = (int*)(ws + 0);
    ushort* srcl = (ushort*)(ws + 196608);
    uint*   xb   = (uint*)(ws + 5373952);
    uint*   hb   = (uint*)(ws + 15728640);
    ushort* h1b  = (ushort*)(ws + 26083328);
    uint*   w1b  = (uint*)(ws + 36438016);
    uint*   w2b  = (uint*)(ws + 36503552);
    float*  bn   = (float*)(ws + 36569088);
    float* bnsum   = bn;
    float* bnsumsq = bn + 128;

    k_pre<<<2673, 256, 0, stream>>>(x, W1, W2, cnt, bn, xb, w1b, w2b);
    k_bucket<<<2500, 256, 0, stream>>>(ei, cnt, srcl);
    k_gather<<<10000, 256, 0, stream>>>(xb, cnt, srcl, eps, hb);
    k_mm1<<<625, 256, 0, stream>>>((const ushort*)hb, (const ushort*)w1b, b1, h1b, bnsum, bnsumsq);
    k_mm2<<<625, 256, 0, stream>>>(h1b, (const ushort*)w2b, b2, bnsum, bnsumsq, gamma, beta, (float*)d_out);
}